// Round 16
// baseline (541.577 us; speedup 1.0000x reference)
//
#include <hip/hip_runtime.h>

#define NF 481
#define NT 500
#define CH 16
#define HID 32
#define NB 16
#define NSEQ (NB*NF)   // 7696

typedef __attribute__((ext_vector_type(8))) short short8;
typedef __attribute__((ext_vector_type(4))) float f32x4;

union S8U4 { short8 s; uint4 u; };

// fast sigmoid — v_rcp instead of correctly-rounded divide
__device__ __forceinline__ float sig_(float v) {
    return __builtin_amdgcn_rcpf(1.0f + __expf(-v));
}
// sigmoid for PRE-SCALED logits: v = log2e * x  ->  1/(1+2^-v).
__device__ __forceinline__ float sige_(float v) {
    float e;
    asm("v_exp_f32 %0, -%1" : "=v"(e) : "v"(v));
    return __builtin_amdgcn_rcpf(1.0f + e);
}

__device__ __forceinline__ unsigned short f2bf(float f) {
    unsigned u = __float_as_uint(f);
    u = (u + 0x7fffu + ((u >> 16) & 1u)) >> 16;   // RNE
    return (unsigned short)u;
}
__device__ __forceinline__ unsigned int pk2(float a, float b) {
    return (unsigned int)f2bf(a) | ((unsigned int)f2bf(b) << 16);
}
__device__ __forceinline__ float bf2f(short s) {
    return __uint_as_float(((unsigned)(unsigned short)s) << 16);
}

// -------------------------------------------------------------------------
// Pass 1 (R15 structure): conv1 via MFMA, 8 output f per block.
// -------------------------------------------------------------------------
__global__ __launch_bounds__(256) void conv1_kernel(
    const float* __restrict__ feat,
    const float* __restrict__ w1, const float* __restrict__ b1, const float* __restrict__ a1p,
    unsigned short* __restrict__ y1)          // (b, f, t, ch) bf16
{
    __shared__ unsigned short fhi[16*128*4];  // 16 KB  [row][t][d]
    __shared__ unsigned short flo[16*128*4];  // 16 KB
    const int b    = blockIdx.x;
    const int f0   = blockIdx.y * 8;
    const int tg   = blockIdx.z * 128;
    const int tid  = threadIdx.x;
    const int wid  = tid >> 6;
    const int lane = tid & 63;
    const int c    = lane & 15;
    const int quad = lane >> 4;

    // ---- stage: rows f0-4 .. f0+11 (zero outside f-range), hi/lo bf16 ----
    #pragma unroll
    for (int i = 0; i < 8; i++) {
        const int row = i*2 + (tid >> 7);     // 0..15
        const int tt  = tid & 127;
        const int gf  = f0 - 4 + row;
        const int gt  = (tg + tt < NT) ? (tg + tt) : (NT - 1);
        float v0 = 0.f, v1 = 0.f, v2 = 0.f, v3 = 0.f;
        if (gf >= 0 && gf < NF) {
            v0 = feat[((size_t)(b*4 + 0)*NF + gf)*NT + gt];
            v1 = feat[((size_t)(b*4 + 1)*NF + gf)*NT + gt];
            v2 = feat[((size_t)(b*4 + 2)*NF + gf)*NT + gt];
            v3 = feat[((size_t)(b*4 + 3)*NF + gf)*NT + gt];
        }
        unsigned ph01, ph23;
        asm("v_cvt_pk_bf16_f32 %0, %1, %2" : "=v"(ph01) : "v"(v0), "v"(v1));
        asm("v_cvt_pk_bf16_f32 %0, %1, %2" : "=v"(ph23) : "v"(v2), "v"(v3));
        const float h0f = __uint_as_float(ph01 << 16);
        const float h1f = __uint_as_float(ph01 & 0xffff0000u);
        const float h2f = __uint_as_float(ph23 << 16);
        const float h3f = __uint_as_float(ph23 & 0xffff0000u);
        unsigned pl01, pl23;
        asm("v_cvt_pk_bf16_f32 %0, %1, %2" : "=v"(pl01) : "v"(v0 - h0f), "v"(v1 - h1f));
        asm("v_cvt_pk_bf16_f32 %0, %1, %2" : "=v"(pl23) : "v"(v2 - h2f), "v"(v3 - h3f));
        *(uint2*)&fhi[(row*128 + tt)*4] = make_uint2(ph01, ph23);
        *(uint2*)&flo[(row*128 + tt)*4] = make_uint2(pl01, pl23);
    }
    __syncthreads();

    short8 Whi0, Wlo0, Whi1, Wlo1;
    { _Pragma("unroll") for (int j = 0; j < 8; j++) {
        {
            const int kk = quad*2 + (j >> 2);
            const int d  = j & 3;
            const float w = w1[c*36 + d*9 + kk];
            const unsigned short hb = f2bf(w);
            Whi0[j] = (short)hb;
            Wlo0[j] = (short)f2bf(w - bf2f((short)hb));
        }
        {
            float w = 0.f;
            if (quad == 0 && j < 4) w = w1[c*36 + (j & 3)*9 + 8];
            const unsigned short hb = f2bf(w);
            Whi1[j] = (short)hb;
            Wlo1[j] = (short)f2bf(w - bf2f((short)hb));
        }
    } }

    const float al1 = a1p[0];
    const f32x4 cb = {b1[quad*4 + 0], b1[quad*4 + 1],
                      b1[quad*4 + 2], b1[quad*4 + 3]};

    #pragma unroll
    for (int e = 0; e < 2; e++) {
        const int fl = wid*2 + e;             // local output row 0..7
        const int f  = f0 + fl;
        unsigned short* xo = y1 + ((size_t)(b*NF + ((f < NF) ? f : 0))*NT)*CH + quad*4;
        #pragma unroll
        for (int ti = 0; ti < 8; ti++) {
            const int t  = ti*16 + c;
            const int r0 = fl + quad*2;
            const uint2 dh0 = *(const uint2*)&fhi[((r0    )*128 + t)*4];
            const uint2 dh1 = *(const uint2*)&fhi[((r0 + 1)*128 + t)*4];
            const uint2 dl0 = *(const uint2*)&flo[((r0    )*128 + t)*4];
            const uint2 dl1 = *(const uint2*)&flo[((r0 + 1)*128 + t)*4];
            uint2 dh2 = *(const uint2*)&fhi[((fl + 8)*128 + t)*4];
            uint2 dl2 = *(const uint2*)&flo[((fl + 8)*128 + t)*4];
            if (quad != 0) { dh2 = make_uint2(0u, 0u); dl2 = make_uint2(0u, 0u); }

            S8U4 Dhi0, Dlo0, Dhi1, Dlo1;
            Dhi0.u = make_uint4(dh0.x, dh0.y, dh1.x, dh1.y);
            Dlo0.u = make_uint4(dl0.x, dl0.y, dl1.x, dl1.y);
            Dhi1.u = make_uint4(dh2.x, dh2.y, 0u, 0u);
            Dlo1.u = make_uint4(dl2.x, dl2.y, 0u, 0u);

            f32x4 acc = cb;
            acc = __builtin_amdgcn_mfma_f32_16x16x32_bf16(Whi0, Dhi0.s, acc, 0, 0, 0);
            acc = __builtin_amdgcn_mfma_f32_16x16x32_bf16(Whi0, Dlo0.s, acc, 0, 0, 0);
            acc = __builtin_amdgcn_mfma_f32_16x16x32_bf16(Wlo0, Dhi0.s, acc, 0, 0, 0);
            acc = __builtin_amdgcn_mfma_f32_16x16x32_bf16(Whi1, Dhi1.s, acc, 0, 0, 0);
            acc = __builtin_amdgcn_mfma_f32_16x16x32_bf16(Whi1, Dlo1.s, acc, 0, 0, 0);
            acc = __builtin_amdgcn_mfma_f32_16x16x32_bf16(Wlo1, Dhi1.s, acc, 0, 0, 0);

            const int tt = tg + t;
            if (tt < NT && f < NF) {
                float v0 = acc[0], v1 = acc[1], v2 = acc[2], v3 = acc[3];
                v0 = (v0 >= 0.f) ? v0 : al1*v0;
                v1 = (v1 >= 0.f) ? v1 : al1*v1;
                v2 = (v2 >= 0.f) ? v2 : al1*v2;
                v3 = (v3 >= 0.f) ? v3 : al1*v3;
                *(uint2*)(xo + (size_t)tt*CH) = make_uint2(pk2(v0, v1), pk2(v2, v3));
            }
        }
    }
}

// -------------------------------------------------------------------------
// GRU + fused conv2 (R16).  conv2 never materializes x: the gru wave builds
// ONE conv2 tile per step (16 t x 16 ch for one of its 16 seqs), double-
// buffered in LDS chunks of 16 steps.  Tile loads issued one step ahead
// (latency hidden under the 1390-cyc step); x read from LDS prefetched one
// step ahead.  seq stride 264 elem makes both LDS accesses ~2-way (free).
// Adds ~120 cyc/step; deletes the entire conv2 kernel + xbuf round trip.
// -------------------------------------------------------------------------
__global__ __launch_bounds__(64) void gru_kernel(
    const unsigned short* __restrict__ y1,   // (b, f, t, ch) bf16 (conv1 out)
    const float* __restrict__ h0,    // (NSEQ, 32)
    const float* __restrict__ w_ih,  // (96, 16)
    const float* __restrict__ w_hh,  // (96, 32)
    const float* __restrict__ b_ih, const float* __restrict__ b_hh,
    const float* __restrict__ fc_w, const float* __restrict__ fc_b,
    const float* __restrict__ w2, const float* __restrict__ b2, const float* __restrict__ a2p,
    float* __restrict__ prob,        // (NSEQ, NT)
    float* __restrict__ hout)        // (NSEQ, 32)
{
    __shared__ unsigned short x16[2][16*264];   // double-buffered x chunks
    const int lane = threadIdx.x & 63;
    const int c    = lane & 15;
    const int quad = lane >> 4;
    const int base = blockIdx.x * 16;        // 481 blocks x 16 seq
    const float L2E = 1.4426950408889634f;
    const short8 zero8 = {0,0,0,0,0,0,0,0};

    // ===== GRU weight fragments (R10 verbatim) =====
    const int ub = (quad == 0) ? 16 : (quad == 1) ? 24 : (quad == 2) ? 0 : 8;
    const int cq  = c >> 2;
    const int ubr = (cq == 0) ? 16 : (cq == 1) ? 24 : (cq == 2) ? 0 : 8;
    const int uA  = ubr + (c & 3);
    const int uB  = uA + 4;

    #define BLDR(DST, CK, GROW)                                                \
        { _Pragma("unroll") for (int j = 0; j < 8; j++) {                      \
            const int k = (CK)*32 + quad*8 + j;                                \
            float wv_ = 0.f;                                                   \
            if (k < 16)      wv_ = w_ih[(GROW)*16 + k];                        \
            else if (k < 48) wv_ = w_hh[(GROW)*32 + k - 16];                   \
            DST[j] = (short)f2bf(wv_ * L2E); } }
    #define BLDX(DST, U)                                                       \
        { _Pragma("unroll") for (int j = 0; j < 8; j++) {                      \
            const int k = quad*8 + j;                                          \
            float wv_ = (k < 16) ? w_ih[(64+(U))*16 + k] : 0.f;                \
            DST[j] = (short)f2bf(wv_ * 2.f*L2E); } }
    #define BLDH(DST, CK, U)                                                   \
        { _Pragma("unroll") for (int j = 0; j < 8; j++) {                      \
            const int k = (CK)*32 + quad*8 + j;                                \
            float wv_ = (k >= 16 && k < 48) ? w_hh[(64+(U))*32 + k - 16] : 0.f;\
            DST[j] = (short)f2bf(wv_ * 2.f*L2E); } }
    #define BLDF(DST, CK)                                                      \
        { _Pragma("unroll") for (int j = 0; j < 8; j++) {                      \
            const int k = (CK)*32 + quad*8 + j;                                \
            float wv_ = (k >= 16 && k < 48) ? fc_w[k - 16] : 0.f;              \
            DST[j] = (short)f2bf(wv_); } }

    short8 WRaA, WRbA, WRaB, WRbB;
    short8 WZaA, WZbA, WZaB, WZbB;
    short8 WXaA, WXaB;
    short8 WHaA, WHbA, WHaB, WHbB;
    short8 WFa, WFb;
    BLDR(WRaA, 0, uA);     BLDR(WRbA, 1, uA);
    BLDR(WRaB, 0, uB);     BLDR(WRbB, 1, uB);
    BLDR(WZaA, 0, 32+uA);  BLDR(WZbA, 1, 32+uA);
    BLDR(WZaB, 0, 32+uB);  BLDR(WZbB, 1, 32+uB);
    BLDX(WXaA, uA);        BLDX(WXaB, uB);
    BLDH(WHaA, 0, uA);     BLDH(WHbA, 1, uA);
    BLDH(WHaB, 0, uB);     BLDH(WHbB, 1, uB);
    BLDF(WFa, 0);          BLDF(WFb, 1);

    // ===== conv2 weight fragments (R14 verbatim build; srcA row = c = cout)
    short8 C2h0, C2h1, C2h2, C2l0, C2l1, C2l2;
    #define MKB2(BH, BL, Q)                                                    \
        { _Pragma("unroll") for (int j = 0; j < 8; j++) {                      \
            const int ci = (quad & 1)*8 + j;                                   \
            const int kk = 2*(Q) + (quad >> 1);                                \
            float w = 0.f;                                                     \
            if (kk < 5) w = w2[c*80 + ci*5 + kk];                              \
            const unsigned short hb = f2bf(w);                                 \
            const float hf = bf2f((short)hb);                                  \
            BH[j] = (short)hb;                                                 \
            BL[j] = (short)f2bf(w - hf); } }
    MKB2(C2h0, C2l0, 0); MKB2(C2h1, C2l1, 1); MKB2(C2h2, C2l2, 2);
    #undef MKB2
    const float al2 = a2p[0];
    const f32x4 cbC2 = {b2[quad*4 + 0], b2[quad*4 + 1],
                        b2[quad*4 + 2], b2[quad*4 + 3]};
    const int ci0 = (quad & 1)*8;
    const int r0q = quad >> 1;               // fragment row offset (0 or 1)
    const int b0c = base / NF;
    const int f0c = base - b0c*NF;

    // tile pointer/validity setup for tile S of chunk starting at T0
    #define TILEPTR(S, T0, P0_, P1_, P2_, OK0_, OK1_, OK2_)                    \
        {                                                                      \
            int fs_ = f0c + (S); int bs_ = b0c;                                \
            if (fs_ >= NF) { fs_ -= NF; bs_ += 1; }                            \
            const int fy0_ = fs_ - 2 + r0q;                                    \
            const int fy1_ = fs_ + r0q;                                        \
            const int fy2_ = fs_ + 2;                                          \
            OK0_ = (fy0_ >= 0);                                                \
            OK1_ = (fy1_ < NF);                                                \
            OK2_ = (r0q == 0) && (fy2_ < NF);                                  \
            const int tc_ = ((T0) + c < NT) ? ((T0) + c) : (NT - 1);           \
            P0_ = y1 + ((size_t)(bs_*NF + (OK0_ ? fy0_ : 0))*NT + tc_)*CH + ci0; \
            P1_ = y1 + ((size_t)(bs_*NF + (OK1_ ? fy1_ : 0))*NT + tc_)*CH + ci0; \
            P2_ = y1 + ((size_t)(bs_*NF + (OK2_ ? fy2_ : 0))*NT + tc_)*CH + ci0; \
        }

    // one conv2 tile: D row = quad*4+r = cout, col = c = t; write to buf/row S
    #define C2TILE(D0_, D1_, D2_, BUF_, S_)                                    \
        {                                                                      \
            f32x4 ac_ = cbC2;                                                  \
            ac_ = __builtin_amdgcn_mfma_f32_16x16x32_bf16(C2l0, D0_, ac_, 0, 0, 0); \
            ac_ = __builtin_amdgcn_mfma_f32_16x16x32_bf16(C2l1, D1_, ac_, 0, 0, 0); \
            ac_ = __builtin_amdgcn_mfma_f32_16x16x32_bf16(C2l2, D2_, ac_, 0, 0, 0); \
            ac_ = __builtin_amdgcn_mfma_f32_16x16x32_bf16(C2h0, D0_, ac_, 0, 0, 0); \
            ac_ = __builtin_amdgcn_mfma_f32_16x16x32_bf16(C2h1, D1_, ac_, 0, 0, 0); \
            ac_ = __builtin_amdgcn_mfma_f32_16x16x32_bf16(C2h2, D2_, ac_, 0, 0, 0); \
            float w0_ = ac_[0], w1_ = ac_[1], w2_ = ac_[2], w3_ = ac_[3];      \
            w0_ = (w0_ >= 0.f) ? w0_ : al2*w0_;                                \
            w1_ = (w1_ >= 0.f) ? w1_ : al2*w1_;                                \
            w2_ = (w2_ >= 0.f) ? w2_ : al2*w2_;                                \
            w3_ = (w3_ >= 0.f) ? w3_ : al2*w3_;                                \
            *(uint2*)&x16[BUF_][(S_)*264 + c*16 + quad*4] =                    \
                make_uint2(pk2(w0_, w1_), pk2(w2_, w3_));                      \
        }

    // ===== GRU biases / state (R10 verbatim) =====
    const float4 biA = *(const float4*)(b_ih + ub);
    const float4 biB = *(const float4*)(b_ih + ub + 4);
    const float4 bhA = *(const float4*)(b_hh + ub);
    const float4 bhB = *(const float4*)(b_hh + ub + 4);
    const float4 ziA = *(const float4*)(b_ih + 32 + ub);
    const float4 ziB = *(const float4*)(b_ih + 36 + ub);
    const float4 zhA = *(const float4*)(b_hh + 32 + ub);
    const float4 zhB = *(const float4*)(b_hh + 36 + ub);
    const float4 niA = *(const float4*)(b_ih + 64 + ub);
    const float4 niB = *(const float4*)(b_ih + 68 + ub);
    const float4 nhA = *(const float4*)(b_hh + 64 + ub);
    const float4 nhB = *(const float4*)(b_hh + 68 + ub);
    const f32x4 cbRA = {(biA.x+bhA.x)*L2E, (biA.y+bhA.y)*L2E, (biA.z+bhA.z)*L2E, (biA.w+bhA.w)*L2E};
    const f32x4 cbRB = {(biB.x+bhB.x)*L2E, (biB.y+bhB.y)*L2E, (biB.z+bhB.z)*L2E, (biB.w+bhB.w)*L2E};
    const f32x4 cbZA = {(ziA.x+zhA.x)*L2E, (ziA.y+zhA.y)*L2E, (ziA.z+zhA.z)*L2E, (ziA.w+zhA.w)*L2E};
    const f32x4 cbZB = {(ziB.x+zhB.x)*L2E, (ziB.y+zhB.y)*L2E, (ziB.z+zhB.z)*L2E, (ziB.w+zhB.w)*L2E};
    const f32x4 cbXA = {niA.x*2.f*L2E, niA.y*2.f*L2E, niA.z*2.f*L2E, niA.w*2.f*L2E};
    const f32x4 cbXB = {niB.x*2.f*L2E, niB.y*2.f*L2E, niB.z*2.f*L2E, niB.w*2.f*L2E};
    const f32x4 cbHA = {nhA.x*2.f*L2E, nhA.y*2.f*L2E, nhA.z*2.f*L2E, nhA.w*2.f*L2E};
    const f32x4 cbHB = {nhB.x*2.f*L2E, nhB.y*2.f*L2E, nhB.z*2.f*L2E, nhB.w*2.f*L2E};
    const float fb = fc_b[0];
    const f32x4 cbF = {fb, fb, fb, fb};

    const float* hrow = h0 + (size_t)(base + c)*HID + ub;
    float h0_ = hrow[0], h1_ = hrow[1], h2_ = hrow[2], h3_ = hrow[3];
    float h4_ = hrow[4], h5_ = hrow[5], h6_ = hrow[6], h7_ = hrow[7];

    // ===== prologue: build chunk 0 (tiles 0..15, buf 0) =====
    {
        #pragma unroll 2
        for (int s = 0; s < 16; s++) {
            const unsigned short *q0, *q1, *q2;
            bool o0, o1, o2;
            TILEPTR(s, 0, q0, q1, q2, o0, o1, o2);
            short8 d0 = o0 ? *(const short8*)q0 : zero8;
            short8 d1 = o1 ? *(const short8*)q1 : zero8;
            short8 d2 = o2 ? *(const short8*)q2 : zero8;
            C2TILE(d0, d1, d2, 0, s);
        }
    }
    // preload tile 0 of chunk 1 into the rolling load regs
    const unsigned short *pA0, *pA1, *pA2;
    bool okA0, okA1, okA2;
    TILEPTR(0, 16, pA0, pA1, pA2, okA0, okA1, okA2);
    short8 La0 = *(const short8*)pA0;
    short8 La1 = *(const short8*)pA1;
    short8 La2 = *(const short8*)pA2;
    // x for t = 0 (chunk 0 fully written by this wave)
    asm volatile("s_waitcnt lgkmcnt(0)" ::: "memory");
    uint4 xcur = *(const uint4*)&x16[0][c*264 + 0*16 + (quad & 1)*8];

    #define PACKH(HA)                                                          \
        { unsigned p0_, p1_, p2_, p3_;                                         \
          asm("v_cvt_pk_bf16_f32 %0, %1, %2" : "=v"(p0_) : "v"(h0_), "v"(h1_));\
          asm("v_cvt_pk_bf16_f32 %0, %1, %2" : "=v"(p1_) : "v"(h2_), "v"(h3_));\
          asm("v_cvt_pk_bf16_f32 %0, %1, %2" : "=v"(p2_) : "v"(h4_), "v"(h5_));\
          asm("v_cvt_pk_bf16_f32 %0, %1, %2" : "=v"(p3_) : "v"(h6_), "v"(h7_));\
          S8U4 hu_; hu_.u = make_uint4(p0_, p1_, p2_, p3_);                    \
          HA = hu_.s; }

    #define GS(ACR, ACZ, ACX, ACH, R, HREG)                                    \
        {                                                                      \
            const float rr = sige_(ACR[R]);                                    \
            const float zz = sige_(ACZ[R]);                                    \
            const float aa = fmaf(rr, ACH[R], ACX[R]);                         \
            const float nn = fmaf(2.f, sige_(aa), -1.f);                       \
            HREG = fmaf(zz, HREG - nn, nn);                                    \
        }

    for (int t = 0; t < NT; t++) {
        // ---- conv2 pipeline: finish tile (t&15) of chunk (t>>4)+1 ----
        {
            const int sM  = t & 15;
            const int bufM = ((t >> 4) + 1) & 1;
            short8 d0 = okA0 ? La0 : zero8;
            short8 d1 = okA1 ? La1 : zero8;
            short8 d2 = okA2 ? La2 : zero8;
            C2TILE(d0, d1, d2, bufM, sM);
        }
        // ---- issue loads for the NEXT tile ----
        {
            const int tp = t + 1;
            const int sL = tp & 15;
            const int KL = (tp >> 4) + 1;
            TILEPTR(sL, KL*16, pA0, pA1, pA2, okA0, okA1, okA2);
            La0 = *(const short8*)pA0;
            La1 = *(const short8*)pA1;
            La2 = *(const short8*)pA2;
        }
        // ---- x prefetch for t+1 (fence only at chunk tail: RAW on same buf)
        if ((t & 15) == 15) asm volatile("s_waitcnt lgkmcnt(0)" ::: "memory");
        uint4 xnext;
        {
            const int tp = t + 1;
            xnext = *(const uint4*)&x16[(tp >> 4) & 1][c*264 + (tp & 15)*16 + (quad & 1)*8];
        }

        // ---- GRU step (R10 verbatim, x from xcur) ----
        short8 ha; PACKH(ha);
        S8U4 xu; xu.u = xcur;
        const short8 a0 = (quad < 2) ? xu.s : ha;      // k0-31: x | h0-15
        const short8 a1 = (quad < 2) ? ha   : zero8;   // k32-63: h16-31 | pad

        f32x4 aRA = __builtin_amdgcn_mfma_f32_16x16x32_bf16(WRaA, a0, cbRA, 0, 0, 0);
        f32x4 aRB = __builtin_amdgcn_mfma_f32_16x16x32_bf16(WRaB, a0, cbRB, 0, 0, 0);
        f32x4 aZA = __builtin_amdgcn_mfma_f32_16x16x32_bf16(WZaA, a0, cbZA, 0, 0, 0);
        f32x4 aZB = __builtin_amdgcn_mfma_f32_16x16x32_bf16(WZaB, a0, cbZB, 0, 0, 0);
        f32x4 aXA = __builtin_amdgcn_mfma_f32_16x16x32_bf16(WXaA, a0, cbXA, 0, 0, 0);
        f32x4 aXB = __builtin_amdgcn_mfma_f32_16x16x32_bf16(WXaB, a0, cbXB, 0, 0, 0);
        f32x4 aHA = __builtin_amdgcn_mfma_f32_16x16x32_bf16(WHaA, a0, cbHA, 0, 0, 0);
        f32x4 aHB = __builtin_amdgcn_mfma_f32_16x16x32_bf16(WHaB, a0, cbHB, 0, 0, 0);
        f32x4 aF  = __builtin_amdgcn_mfma_f32_16x16x32_bf16(WFa,  a0, cbF,  0, 0, 0);
        aRA = __builtin_amdgcn_mfma_f32_16x16x32_bf16(WRbA, a1, aRA, 0, 0, 0);
        aRB = __builtin_amdgcn_mfma_f32_16x16x32_bf16(WRbB, a1, aRB, 0, 0, 0);
        aZA = __builtin_amdgcn_mfma_f32_16x16x32_bf16(WZbA, a1, aZA, 0, 0, 0);
        aZB = __builtin_amdgcn_mfma_f32_16x16x32_bf16(WZbB, a1, aZB, 0, 0, 0);
        aHA = __builtin_amdgcn_mfma_f32_16x16x32_bf16(WHbA, a1, aHA, 0, 0, 0);
        aHB = __builtin_amdgcn_mfma_f32_16x16x32_bf16(WHbB, a1, aHB, 0, 0, 0);
        aF  = __builtin_amdgcn_mfma_f32_16x16x32_bf16(WFb,  a1, aF,  0, 0, 0);

        if (t > 0 && lane < 16)
            prob[(size_t)(base + c)*NT + (t - 1)] = sig_(aF[0]);

        GS(aRA, aZA, aXA, aHA, 0, h0_);
        GS(aRA, aZA, aXA, aHA, 1, h1_);
        GS(aRA, aZA, aXA, aHA, 2, h2_);
        GS(aRA, aZA, aXA, aHA, 3, h3_);
        GS(aRB, aZB, aXB, aHB, 0, h4_);
        GS(aRB, aZB, aXB, aHB, 1, h5_);
        GS(aRB, aZB, aXB, aHB, 2, h6_);
        GS(aRB, aZB, aXB, aHB, 3, h7_);

        xcur = xnext;
    }

    // final prob (FC on h(NT))
    {
        short8 ha; PACKH(ha);
        const short8 a0f = (quad < 2) ? zero8 : ha;
        const short8 a1f = (quad < 2) ? ha    : zero8;
        f32x4 aF = __builtin_amdgcn_mfma_f32_16x16x32_bf16(WFa, a0f, cbF, 0, 0, 0);
        aF = __builtin_amdgcn_mfma_f32_16x16x32_bf16(WFb, a1f, aF, 0, 0, 0);
        if (lane < 16)
            prob[(size_t)(base + c)*NT + (NT - 1)] = sig_(aF[0]);
    }

    float* ho = hout + (size_t)(base + c)*HID + ub;
    *(float4*)(ho)     = make_float4(h0_, h1_, h2_, h3_);
    *(float4*)(ho + 4) = make_float4(h4_, h5_, h6_, h7_);
}

// -------------------------------------------------------------------------
extern "C" void kernel_launch(void* const* d_in, const int* in_sizes, int n_in,
                              void* d_out, int out_size, void* d_ws, size_t ws_size,
                              hipStream_t stream)
{
    const float* feat = (const float*)d_in[0];
    const float* h0   = (const float*)d_in[1];
    const float* w1   = (const float*)d_in[2];
    const float* b1   = (const float*)d_in[3];
    const float* a1   = (const float*)d_in[4];
    const float* w2   = (const float*)d_in[5];
    const float* b2   = (const float*)d_in[6];
    const float* a2   = (const float*)d_in[7];
    const float* wih  = (const float*)d_in[8];
    const float* whh  = (const float*)d_in[9];
    const float* bih  = (const float*)d_in[10];
    const float* bhh  = (const float*)d_in[11];
    const float* fcw  = (const float*)d_in[12];
    const float* fcb  = (const float*)d_in[13];

    unsigned short* y1 = (unsigned short*)d_ws;              // 123.1 MB bf16 (b,f,t,ch)
    float* prob = (float*)d_out;                             // (B, F, T)
    float* hout = prob + (size_t)NSEQ*NT;                    // (1, NSEQ, 32)

    dim3 c1grid(NB, 61, 4);                                  // 8 f x 128 t per block
    conv1_kernel<<<c1grid, 256, 0, stream>>>(feat, w1, b1, a1, y1);
    gru_kernel<<<NSEQ/16, 64, 0, stream>>>(y1, h0, wih, whh, bih, bhh, fcw, fcb,
                                           w2, b2, a2, prob, hout);
}

// Round 17
// 499.289 us; speedup vs baseline: 1.0847x; 1.0847x over previous
//
#include <hip/hip_runtime.h>

#define NF 481
#define NT 500
#define CH 16
#define HID 32
#define NB 16
#define NSEQ (NB*NF)   // 7696

typedef __attribute__((ext_vector_type(8))) short short8;
typedef __attribute__((ext_vector_type(4))) float f32x4;

union S8U4 { short8 s; uint4 u; };

// fast sigmoid — v_rcp instead of correctly-rounded divide
__device__ __forceinline__ float sig_(float v) {
    return __builtin_amdgcn_rcpf(1.0f + __expf(-v));
}
// sigmoid for PRE-SCALED logits: v = log2e * x  ->  1/(1+2^-v).
__device__ __forceinline__ float sige_(float v) {
    float e;
    asm("v_exp_f32 %0, -%1" : "=v"(e) : "v"(v));
    return __builtin_amdgcn_rcpf(1.0f + e);
}

__device__ __forceinline__ unsigned short f2bf(float f) {
    unsigned u = __float_as_uint(f);
    u = (u + 0x7fffu + ((u >> 16) & 1u)) >> 16;   // RNE
    return (unsigned short)u;
}
__device__ __forceinline__ unsigned int pk2(float a, float b) {
    return (unsigned int)f2bf(a) | ((unsigned int)f2bf(b) << 16);
}
__device__ __forceinline__ float bf2f(short s) {
    return __uint_as_float(((unsigned)(unsigned short)s) << 16);
}

// -------------------------------------------------------------------------
// Pass 1 (R15 verbatim): conv1 via MFMA, 8 output f per block.
// -------------------------------------------------------------------------
__global__ __launch_bounds__(256) void conv1_kernel(
    const float* __restrict__ feat,
    const float* __restrict__ w1, const float* __restrict__ b1, const float* __restrict__ a1p,
    unsigned short* __restrict__ y1)          // (b, f, t, ch) bf16
{
    __shared__ unsigned short fhi[16*128*4];  // 16 KB  [row][t][d]
    __shared__ unsigned short flo[16*128*4];  // 16 KB
    const int b    = blockIdx.x;
    const int f0   = blockIdx.y * 8;
    const int tg   = blockIdx.z * 128;
    const int tid  = threadIdx.x;
    const int wid  = tid >> 6;
    const int lane = tid & 63;
    const int c    = lane & 15;
    const int quad = lane >> 4;

    // ---- stage: rows f0-4 .. f0+11 (zero outside f-range), hi/lo bf16 ----
    #pragma unroll
    for (int i = 0; i < 8; i++) {
        const int row = i*2 + (tid >> 7);     // 0..15
        const int tt  = tid & 127;
        const int gf  = f0 - 4 + row;
        const int gt  = (tg + tt < NT) ? (tg + tt) : (NT - 1);
        float v0 = 0.f, v1 = 0.f, v2 = 0.f, v3 = 0.f;
        if (gf >= 0 && gf < NF) {
            v0 = feat[((size_t)(b*4 + 0)*NF + gf)*NT + gt];
            v1 = feat[((size_t)(b*4 + 1)*NF + gf)*NT + gt];
            v2 = feat[((size_t)(b*4 + 2)*NF + gf)*NT + gt];
            v3 = feat[((size_t)(b*4 + 3)*NF + gf)*NT + gt];
        }
        unsigned ph01, ph23;
        asm("v_cvt_pk_bf16_f32 %0, %1, %2" : "=v"(ph01) : "v"(v0), "v"(v1));
        asm("v_cvt_pk_bf16_f32 %0, %1, %2" : "=v"(ph23) : "v"(v2), "v"(v3));
        const float h0f = __uint_as_float(ph01 << 16);
        const float h1f = __uint_as_float(ph01 & 0xffff0000u);
        const float h2f = __uint_as_float(ph23 << 16);
        const float h3f = __uint_as_float(ph23 & 0xffff0000u);
        unsigned pl01, pl23;
        asm("v_cvt_pk_bf16_f32 %0, %1, %2" : "=v"(pl01) : "v"(v0 - h0f), "v"(v1 - h1f));
        asm("v_cvt_pk_bf16_f32 %0, %1, %2" : "=v"(pl23) : "v"(v2 - h2f), "v"(v3 - h3f));
        *(uint2*)&fhi[(row*128 + tt)*4] = make_uint2(ph01, ph23);
        *(uint2*)&flo[(row*128 + tt)*4] = make_uint2(pl01, pl23);
    }
    __syncthreads();

    short8 Whi0, Wlo0, Whi1, Wlo1;
    { _Pragma("unroll") for (int j = 0; j < 8; j++) {
        {
            const int kk = quad*2 + (j >> 2);
            const int d  = j & 3;
            const float w = w1[c*36 + d*9 + kk];
            const unsigned short hb = f2bf(w);
            Whi0[j] = (short)hb;
            Wlo0[j] = (short)f2bf(w - bf2f((short)hb));
        }
        {
            float w = 0.f;
            if (quad == 0 && j < 4) w = w1[c*36 + (j & 3)*9 + 8];
            const unsigned short hb = f2bf(w);
            Whi1[j] = (short)hb;
            Wlo1[j] = (short)f2bf(w - bf2f((short)hb));
        }
    } }

    const float al1 = a1p[0];
    const f32x4 cb = {b1[quad*4 + 0], b1[quad*4 + 1],
                      b1[quad*4 + 2], b1[quad*4 + 3]};

    #pragma unroll
    for (int e = 0; e < 2; e++) {
        const int fl = wid*2 + e;             // local output row 0..7
        const int f  = f0 + fl;
        unsigned short* xo = y1 + ((size_t)(b*NF + ((f < NF) ? f : 0))*NT)*CH + quad*4;
        #pragma unroll
        for (int ti = 0; ti < 8; ti++) {
            const int t  = ti*16 + c;
            const int r0 = fl + quad*2;
            const uint2 dh0 = *(const uint2*)&fhi[((r0    )*128 + t)*4];
            const uint2 dh1 = *(const uint2*)&fhi[((r0 + 1)*128 + t)*4];
            const uint2 dl0 = *(const uint2*)&flo[((r0    )*128 + t)*4];
            const uint2 dl1 = *(const uint2*)&flo[((r0 + 1)*128 + t)*4];
            uint2 dh2 = *(const uint2*)&fhi[((fl + 8)*128 + t)*4];
            uint2 dl2 = *(const uint2*)&flo[((fl + 8)*128 + t)*4];
            if (quad != 0) { dh2 = make_uint2(0u, 0u); dl2 = make_uint2(0u, 0u); }

            S8U4 Dhi0, Dlo0, Dhi1, Dlo1;
            Dhi0.u = make_uint4(dh0.x, dh0.y, dh1.x, dh1.y);
            Dlo0.u = make_uint4(dl0.x, dl0.y, dl1.x, dl1.y);
            Dhi1.u = make_uint4(dh2.x, dh2.y, 0u, 0u);
            Dlo1.u = make_uint4(dl2.x, dl2.y, 0u, 0u);

            f32x4 acc = cb;
            acc = __builtin_amdgcn_mfma_f32_16x16x32_bf16(Whi0, Dhi0.s, acc, 0, 0, 0);
            acc = __builtin_amdgcn_mfma_f32_16x16x32_bf16(Whi0, Dlo0.s, acc, 0, 0, 0);
            acc = __builtin_amdgcn_mfma_f32_16x16x32_bf16(Wlo0, Dhi0.s, acc, 0, 0, 0);
            acc = __builtin_amdgcn_mfma_f32_16x16x32_bf16(Whi1, Dhi1.s, acc, 0, 0, 0);
            acc = __builtin_amdgcn_mfma_f32_16x16x32_bf16(Whi1, Dlo1.s, acc, 0, 0, 0);
            acc = __builtin_amdgcn_mfma_f32_16x16x32_bf16(Wlo1, Dhi1.s, acc, 0, 0, 0);

            const int tt = tg + t;
            if (tt < NT && f < NF) {
                float v0 = acc[0], v1 = acc[1], v2 = acc[2], v3 = acc[3];
                v0 = (v0 >= 0.f) ? v0 : al1*v0;
                v1 = (v1 >= 0.f) ? v1 : al1*v1;
                v2 = (v2 >= 0.f) ? v2 : al1*v2;
                v3 = (v3 >= 0.f) ? v3 : al1*v3;
                *(uint2*)(xo + (size_t)tt*CH) = make_uint2(pk2(v0, v1), pk2(v2, v3));
            }
        }
    }
}

// -------------------------------------------------------------------------
// Pass 2 (R17): conv2 via MFMA, direct-global srcB (R14), 512 t per block
// (32 tiles/wave, z-grid = 1) — weight-fragment build + launch fixed cost
// amortized 2x over R15.  1936 blocks ~= 7.6 waves/SIMD for latency hiding.
// -------------------------------------------------------------------------
__global__ __launch_bounds__(256) void conv2_kernel(
    const unsigned short* __restrict__ y1,    // (b, f, t, ch) bf16
    const float* __restrict__ w2, const float* __restrict__ b2, const float* __restrict__ a2p,
    unsigned short* __restrict__ xout)
{
    const int b    = blockIdx.x;
    const int f0   = blockIdx.y * 4;
    const int wid  = threadIdx.x >> 6;
    const int lane = threadIdx.x & 63;
    const int c    = lane & 15;
    const int quad = lane >> 4;
    const int f    = f0 + wid;
    if (f >= NF) return;

    const float al2 = a2p[0];
    short8 Bh0, Bh1, Bh2, Bl0, Bl1, Bl2;
    #define MKB2(BH, BL, Q)                                                    \
        { _Pragma("unroll") for (int j = 0; j < 8; j++) {                      \
            const int ci = (quad & 1)*8 + j;                                   \
            const int kk = 2*(Q) + (quad >> 1);                                \
            float w = 0.f;                                                     \
            if (kk < 5) w = w2[c*80 + ci*5 + kk];                              \
            const unsigned short hb = f2bf(w);                                 \
            const float hf = bf2f((short)hb);                                  \
            BH[j] = (short)hb;                                                 \
            BL[j] = (short)f2bf(w - hf); } }
    MKB2(Bh0, Bl0, 0); MKB2(Bh1, Bl1, 1); MKB2(Bh2, Bl2, 2);
    #undef MKB2

    // bias per ROW: acc[r] is cout = quad*4 + r
    const f32x4 cb = {b2[quad*4 + 0], b2[quad*4 + 1],
                      b2[quad*4 + 2], b2[quad*4 + 3]};
    const int ci0 = (quad & 1)*8;
    const int r0  = wid + (quad >> 1);
    const int rl2 = (r0 + 4 > 7) ? 7 : (r0 + 4);   // kk=5 weight = 0 there
    const int fy0 = f0 - 2 + r0;
    const int fy1 = fy0 + 2;
    const int fy2 = f0 - 2 + rl2;
    const bool ok0 = (fy0 >= 0 && fy0 < NF);
    const bool ok1 = (fy1 >= 0 && fy1 < NF);
    const bool ok2 = (fy2 >= 0 && fy2 < NF);
    const unsigned short* p0 = y1 + ((size_t)(b*NF + (ok0 ? fy0 : 0))*NT)*CH + ci0;
    const unsigned short* p1 = y1 + ((size_t)(b*NF + (ok1 ? fy1 : 0))*NT)*CH + ci0;
    const unsigned short* p2 = y1 + ((size_t)(b*NF + (ok2 ? fy2 : 0))*NT)*CH + ci0;
    const short8 zero8 = {0,0,0,0,0,0,0,0};
    unsigned short* xo = xout + ((size_t)(b*NF + f)*NT)*CH + quad*4;

    #pragma unroll
    for (int ti = 0; ti < 32; ti++) {
        const int tt  = ti*16 + c;                   // 0..511
        const int ttc = (tt < NT) ? tt : (NT - 1);   // clamp: results discarded
        short8 a0 = *(const short8*)(p0 + (size_t)ttc*CH);
        short8 a1 = *(const short8*)(p1 + (size_t)ttc*CH);
        short8 a2 = *(const short8*)(p2 + (size_t)ttc*CH);
        if (!ok0) a0 = zero8;
        if (!ok1) a1 = zero8;
        if (!ok2) a2 = zero8;
        f32x4 acc = cb;
        acc = __builtin_amdgcn_mfma_f32_16x16x32_bf16(Bl0, a0, acc, 0, 0, 0);
        acc = __builtin_amdgcn_mfma_f32_16x16x32_bf16(Bl1, a1, acc, 0, 0, 0);
        acc = __builtin_amdgcn_mfma_f32_16x16x32_bf16(Bl2, a2, acc, 0, 0, 0);
        acc = __builtin_amdgcn_mfma_f32_16x16x32_bf16(Bh0, a0, acc, 0, 0, 0);
        acc = __builtin_amdgcn_mfma_f32_16x16x32_bf16(Bh1, a1, acc, 0, 0, 0);
        acc = __builtin_amdgcn_mfma_f32_16x16x32_bf16(Bh2, a2, acc, 0, 0, 0);
        // D: row = quad*4+r = cout, col = c = t
        if (tt < NT) {
            float v0 = acc[0], v1 = acc[1], v2 = acc[2], v3 = acc[3];
            v0 = (v0 >= 0.f) ? v0 : al2*v0;
            v1 = (v1 >= 0.f) ? v1 : al2*v1;
            v2 = (v2 >= 0.f) ? v2 : al2*v2;
            v3 = (v3 >= 0.f) ? v3 : al2*v3;
            *(uint2*)(xo + (size_t)tt*CH) = make_uint2(pk2(v0, v1), pk2(v2, v3));
        }
    }
}

// -------------------------------------------------------------------------
// GRU — R10 verbatim (proven 290-306 us; all-register operand-swapped, zero
// LDS/barriers).  FROZEN.  R16 confirmed (again): the single-wave loop has
// NO fillable stalls — added work costs its full serial price (+614 cyc/step
// measured for the fused conv2 tile vs ~600 predicted serial).
// -------------------------------------------------------------------------
__global__ __launch_bounds__(64) void gru_kernel(
    const unsigned short* __restrict__ xin,  // (NSEQ, NT, 16) bf16
    const float* __restrict__ h0,    // (NSEQ, 32)
    const float* __restrict__ w_ih,  // (96, 16)
    const float* __restrict__ w_hh,  // (96, 32)
    const float* __restrict__ b_ih, const float* __restrict__ b_hh,
    const float* __restrict__ fc_w, const float* __restrict__ fc_b,
    float* __restrict__ prob,        // (NSEQ, NT)
    float* __restrict__ hout)        // (NSEQ, 32)
{
    const int lane = threadIdx.x & 63;
    const int c    = lane & 15;
    const int quad = lane >> 4;
    const int base = blockIdx.x * 16;        // 481 blocks x 16 seq
    const float L2E = 1.4426950408889634f;

    const int ub = (quad == 0) ? 16 : (quad == 1) ? 24 : (quad == 2) ? 0 : 8;
    const int cq  = c >> 2;
    const int ubr = (cq == 0) ? 16 : (cq == 1) ? 24 : (cq == 2) ? 0 : 8;
    const int uA  = ubr + (c & 3);
    const int uB  = uA + 4;

    #define BLDR(DST, CK, GROW)                                                \
        { _Pragma("unroll") for (int j = 0; j < 8; j++) {                      \
            const int k = (CK)*32 + quad*8 + j;                                \
            float wv_ = 0.f;                                                   \
            if (k < 16)      wv_ = w_ih[(GROW)*16 + k];                        \
            else if (k < 48) wv_ = w_hh[(GROW)*32 + k - 16];                   \
            DST[j] = (short)f2bf(wv_ * L2E); } }
    #define BLDX(DST, U)                                                       \
        { _Pragma("unroll") for (int j = 0; j < 8; j++) {                      \
            const int k = quad*8 + j;                                          \
            float wv_ = (k < 16) ? w_ih[(64+(U))*16 + k] : 0.f;                \
            DST[j] = (short)f2bf(wv_ * 2.f*L2E); } }
    #define BLDH(DST, CK, U)                                                   \
        { _Pragma("unroll") for (int j = 0; j < 8; j++) {                      \
            const int k = (CK)*32 + quad*8 + j;                                \
            float wv_ = (k >= 16 && k < 48) ? w_hh[(64+(U))*32 + k - 16] : 0.f;\
            DST[j] = (short)f2bf(wv_ * 2.f*L2E); } }
    #define BLDF(DST, CK)                                                      \
        { _Pragma("unroll") for (int j = 0; j < 8; j++) {                      \
            const int k = (CK)*32 + quad*8 + j;                                \
            float wv_ = (k >= 16 && k < 48) ? fc_w[k - 16] : 0.f;              \
            DST[j] = (short)f2bf(wv_); } }

    short8 WRaA, WRbA, WRaB, WRbB;
    short8 WZaA, WZbA, WZaB, WZbB;
    short8 WXaA, WXaB;
    short8 WHaA, WHbA, WHaB, WHbB;
    short8 WFa, WFb;
    BLDR(WRaA, 0, uA);     BLDR(WRbA, 1, uA);
    BLDR(WRaB, 0, uB);     BLDR(WRbB, 1, uB);
    BLDR(WZaA, 0, 32+uA);  BLDR(WZbA, 1, 32+uA);
    BLDR(WZaB, 0, 32+uB);  BLDR(WZbB, 1, 32+uB);
    BLDX(WXaA, uA);        BLDX(WXaB, uB);
    BLDH(WHaA, 0, uA);     BLDH(WHbA, 1, uA);
    BLDH(WHaB, 0, uB);     BLDH(WHbB, 1, uB);
    BLDF(WFa, 0);          BLDF(WFb, 1);

    const float4 biA = *(const float4*)(b_ih + ub);
    const float4 biB = *(const float4*)(b_ih + ub + 4);
    const float4 bhA = *(const float4*)(b_hh + ub);
    const float4 bhB = *(const float4*)(b_hh + ub + 4);
    const float4 ziA = *(const float4*)(b_ih + 32 + ub);
    const float4 ziB = *(const float4*)(b_ih + 36 + ub);
    const float4 zhA = *(const float4*)(b_hh + 32 + ub);
    const float4 zhB = *(const float4*)(b_hh + 36 + ub);
    const float4 niA = *(const float4*)(b_ih + 64 + ub);
    const float4 niB = *(const float4*)(b_ih + 68 + ub);
    const float4 nhA = *(const float4*)(b_hh + 64 + ub);
    const float4 nhB = *(const float4*)(b_hh + 68 + ub);
    const f32x4 cbRA = {(biA.x+bhA.x)*L2E, (biA.y+bhA.y)*L2E, (biA.z+bhA.z)*L2E, (biA.w+bhA.w)*L2E};
    const f32x4 cbRB = {(biB.x+bhB.x)*L2E, (biB.y+bhB.y)*L2E, (biB.z+bhB.z)*L2E, (biB.w+bhB.w)*L2E};
    const f32x4 cbZA = {(ziA.x+zhA.x)*L2E, (ziA.y+zhA.y)*L2E, (ziA.z+zhA.z)*L2E, (ziA.w+zhA.w)*L2E};
    const f32x4 cbZB = {(ziB.x+zhB.x)*L2E, (ziB.y+zhB.y)*L2E, (ziB.z+zhB.z)*L2E, (ziB.w+zhB.w)*L2E};
    const f32x4 cbXA = {niA.x*2.f*L2E, niA.y*2.f*L2E, niA.z*2.f*L2E, niA.w*2.f*L2E};
    const f32x4 cbXB = {niB.x*2.f*L2E, niB.y*2.f*L2E, niB.z*2.f*L2E, niB.w*2.f*L2E};
    const f32x4 cbHA = {nhA.x*2.f*L2E, nhA.y*2.f*L2E, nhA.z*2.f*L2E, nhA.w*2.f*L2E};
    const f32x4 cbHB = {nhB.x*2.f*L2E, nhB.y*2.f*L2E, nhB.z*2.f*L2E, nhB.w*2.f*L2E};
    const float fb = fc_b[0];
    const f32x4 cbF = {fb, fb, fb, fb};

    const float* hrow = h0 + (size_t)(base + c)*HID + ub;
    float h0_ = hrow[0], h1_ = hrow[1], h2_ = hrow[2], h3_ = hrow[3];
    float h4_ = hrow[4], h5_ = hrow[5], h6_ = hrow[6], h7_ = hrow[7];

    const unsigned short* xp = xin + ((size_t)(base + c)*NT)*CH + (quad & 1)*8;
    uint4 xcur = *(const uint4*)(xp);
    uint4 nx1  = *(const uint4*)(xp + 1*CH);
    uint4 nx2  = *(const uint4*)(xp + 2*CH);

    const short8 zero8 = {0,0,0,0,0,0,0,0};

    #define PACKH(HA)                                                          \
        { unsigned p0_, p1_, p2_, p3_;                                         \
          asm("v_cvt_pk_bf16_f32 %0, %1, %2" : "=v"(p0_) : "v"(h0_), "v"(h1_));\
          asm("v_cvt_pk_bf16_f32 %0, %1, %2" : "=v"(p1_) : "v"(h2_), "v"(h3_));\
          asm("v_cvt_pk_bf16_f32 %0, %1, %2" : "=v"(p2_) : "v"(h4_), "v"(h5_));\
          asm("v_cvt_pk_bf16_f32 %0, %1, %2" : "=v"(p3_) : "v"(h6_), "v"(h7_));\
          S8U4 hu_; hu_.u = make_uint4(p0_, p1_, p2_, p3_);                    \
          HA = hu_.s; }

    #define GS(ACR, ACZ, ACX, ACH, R, HREG)                                    \
        {                                                                      \
            const float rr = sige_(ACR[R]);                                    \
            const float zz = sige_(ACZ[R]);                                    \
            const float aa = fmaf(rr, ACH[R], ACX[R]);                         \
            const float nn = fmaf(2.f, sige_(aa), -1.f);                       \
            HREG = fmaf(zz, HREG - nn, nn);                                    \
        }

    for (int t = 0; t < NT; t++) {
        short8 ha; PACKH(ha);
        S8U4 xu; xu.u = xcur;
        const short8 a0 = (quad < 2) ? xu.s : ha;      // k0-31: x | h0-15
        const short8 a1 = (quad < 2) ? ha   : zero8;   // k32-63: h16-31 | pad

        const int tn = (t + 3 < NT) ? t + 3 : NT - 1;
        const uint4 fx = *(const uint4*)(xp + (size_t)tn*CH);

        f32x4 aRA = __builtin_amdgcn_mfma_f32_16x16x32_bf16(WRaA, a0, cbRA, 0, 0, 0);
        f32x4 aRB = __builtin_amdgcn_mfma_f32_16x16x32_bf16(WRaB, a0, cbRB, 0, 0, 0);
        f32x4 aZA = __builtin_amdgcn_mfma_f32_16x16x32_bf16(WZaA, a0, cbZA, 0, 0, 0);
        f32x4 aZB = __builtin_amdgcn_mfma_f32_16x16x32_bf16(WZaB, a0, cbZB, 0, 0, 0);
        f32x4 aXA = __builtin_amdgcn_mfma_f32_16x16x32_bf16(WXaA, a0, cbXA, 0, 0, 0);
        f32x4 aXB = __builtin_amdgcn_mfma_f32_16x16x32_bf16(WXaB, a0, cbXB, 0, 0, 0);
        f32x4 aHA = __builtin_amdgcn_mfma_f32_16x16x32_bf16(WHaA, a0, cbHA, 0, 0, 0);
        f32x4 aHB = __builtin_amdgcn_mfma_f32_16x16x32_bf16(WHaB, a0, cbHB, 0, 0, 0);
        f32x4 aF  = __builtin_amdgcn_mfma_f32_16x16x32_bf16(WFa,  a0, cbF,  0, 0, 0);
        aRA = __builtin_amdgcn_mfma_f32_16x16x32_bf16(WRbA, a1, aRA, 0, 0, 0);
        aRB = __builtin_amdgcn_mfma_f32_16x16x32_bf16(WRbB, a1, aRB, 0, 0, 0);
        aZA = __builtin_amdgcn_mfma_f32_16x16x32_bf16(WZbA, a1, aZA, 0, 0, 0);
        aZB = __builtin_amdgcn_mfma_f32_16x16x32_bf16(WZbB, a1, aZB, 0, 0, 0);
        aHA = __builtin_amdgcn_mfma_f32_16x16x32_bf16(WHbA, a1, aHA, 0, 0, 0);
        aHB = __builtin_amdgcn_mfma_f32_16x16x32_bf16(WHbB, a1, aHB, 0, 0, 0);
        aF  = __builtin_amdgcn_mfma_f32_16x16x32_bf16(WFb,  a1, aF,  0, 0, 0);

        if (t > 0 && lane < 16)
            prob[(size_t)(base + c)*NT + (t - 1)] = sig_(aF[0]);

        GS(aRA, aZA, aXA, aHA, 0, h0_);
        GS(aRA, aZA, aXA, aHA, 1, h1_);
        GS(aRA, aZA, aXA, aHA, 2, h2_);
        GS(aRA, aZA, aXA, aHA, 3, h3_);
        GS(aRB, aZB, aXB, aHB, 0, h4_);
        GS(aRB, aZB, aXB, aHB, 1, h5_);
        GS(aRB, aZB, aXB, aHB, 2, h6_);
        GS(aRB, aZB, aXB, aHB, 3, h7_);

        xcur = nx1; nx1 = nx2; nx2 = fx;
    }

    // final prob (FC on h(NT))
    {
        short8 ha; PACKH(ha);
        const short8 a0f = (quad < 2) ? zero8 : ha;
        const short8 a1f = (quad < 2) ? ha    : zero8;
        f32x4 aF = __builtin_amdgcn_mfma_f32_16x16x32_bf16(WFa, a0f, cbF, 0, 0, 0);
        aF = __builtin_amdgcn_mfma_f32_16x16x32_bf16(WFb, a1f, aF, 0, 0, 0);
        if (lane < 16)
            prob[(size_t)(base + c)*NT + (NT - 1)] = sig_(aF[0]);
    }

    float* ho = hout + (size_t)(base + c)*HID + ub;
    *(float4*)(ho)     = make_float4(h0_, h1_, h2_, h3_);
    *(float4*)(ho + 4) = make_float4(h4_, h5_, h6_, h7_);
}

// -------------------------------------------------------------------------
extern "C" void kernel_launch(void* const* d_in, const int* in_sizes, int n_in,
                              void* d_out, int out_size, void* d_ws, size_t ws_size,
                              hipStream_t stream)
{
    const float* feat = (const float*)d_in[0];
    const float* h0   = (const float*)d_in[1];
    const float* w1   = (const float*)d_in[2];
    const float* b1   = (const float*)d_in[3];
    const float* a1   = (const float*)d_in[4];
    const float* w2   = (const float*)d_in[5];
    const float* b2   = (const float*)d_in[6];
    const float* a2   = (const float*)d_in[7];
    const float* wih  = (const float*)d_in[8];
    const float* whh  = (const float*)d_in[9];
    const float* bih  = (const float*)d_in[10];
    const float* bhh  = (const float*)d_in[11];
    const float* fcw  = (const float*)d_in[12];
    const float* fcb  = (const float*)d_in[13];

    unsigned short* xbuf = (unsigned short*)d_ws;            // 123.1 MB bf16
    unsigned short* y1   = xbuf + (size_t)NSEQ*NT*CH;        // 123.1 MB bf16 (b,f,t,ch)
    float* prob = (float*)d_out;                             // (B, F, T)
    float* hout = prob + (size_t)NSEQ*NT;                    // (1, NSEQ, 32)

    dim3 c1grid(NB, 61, 4);                                  // 8 f x 128 t per block
    conv1_kernel<<<c1grid, 256, 0, stream>>>(feat, w1, b1, a1, y1);
    dim3 c2grid(NB, 121, 1);                                 // 4 f x 512 t per block
    conv2_kernel<<<c2grid, 256, 0, stream>>>(y1, w2, b2, a2, xbuf);
    gru_kernel<<<NSEQ/16, 64, 0, stream>>>(xbuf, h0, wih, whh, bih, bhh, fcw, fcb, prob, hout);
}